// Round 3
// baseline (125.906 us; speedup 1.0000x reference)
//
#include <hip/hip_runtime.h>

// QuinticHermiteSpline: 2^24 fp32 queries, 1024 uniform knots in [0,1].
// R3 = R2 with compile fix: nontemporal builtins need native clang vectors,
// not HIP_vector_type. Structure:
//   k1 (one block): build per-interval Horner coefficients into d_ws.
//       knots are linspace(0,1,1024) -> t = frac(x*1023), no x_l/inv_h/divide.
//       Table: cA[i]={c5,c4,c3,c2}, cB[i]={c1,c0}  (24 B/interval, 24.5 KB).
//   k2 (streaming): coalesced 24.5 KB global->LDS copy, then grid-stride
//       float4 stream: 2 LDS gathers (b128+b64) + 5 FMA per query.
// Roofline: 128 MB HBM stream -> ~20 us floor at 6.3 TB/s; LDS gather ~8 us
// conflict-free (hidden); VALU ~4 us. Memory-bound.

#define N_KNOTS 1024
#define N_INT   1023
#define WS_B_OFF 16384   // byte offset of cB table in d_ws (cA is 16368 B)

typedef float vfloat4 __attribute__((ext_vector_type(4)));

__global__ __launch_bounds__(1024) void build_table_kernel(
    const float* __restrict__ knots,
    const float* __restrict__ fv,      // [3,1024]: y, dy, ddy
    float4* __restrict__ wsA,
    float2* __restrict__ wsB)
{
    int i = threadIdx.x;
    if (i >= N_INT) return;
    const float* __restrict__ y   = fv;
    const float* __restrict__ dy  = fv + N_KNOTS;
    const float* __restrict__ ddy = fv + 2 * N_KNOTS;
    float xl   = knots[i];
    float h    = knots[i + 1] - xl;
    float yl   = y[i],   yr   = y[i + 1];
    float dyl  = dy[i],  dyr  = dy[i + 1];
    float ddyl = ddy[i], ddyr = ddy[i + 1];
    float dY = yr - yl;
    float h2 = 0.5f * h * h;
    float c5 =   6.0f * dY - 3.0f * h * (dyl + dyr)               + h2 * (ddyr - ddyl);
    float c4 = -15.0f * dY + h * (8.0f * dyl + 7.0f * dyr)        - h2 * (2.0f * ddyr - 3.0f * ddyl);
    float c3 =  10.0f * dY - 2.0f * h * (3.0f * dyl + 2.0f * dyr) + h2 * (ddyr - 3.0f * ddyl);
    wsA[i] = make_float4(c5, c4, c3, h2 * ddyl);
    wsB[i] = make_float2(h * dyl, yl);
}

__device__ __forceinline__ float eval_one(float xq,
                                          const float4* __restrict__ cA,
                                          const float2* __restrict__ cB) {
    float s = xq * 1023.0f;
    int idx = (int)s;
    idx = min(max(idx, 0), N_INT - 1);
    float t = s - (float)idx;          // == frac(s) for in-range x
    float4 a = cA[idx];                // {c5, c4, c3, c2}
    float2 b = cB[idx];                // {c1, c0}
    float v = fmaf(a.x, t, a.y);
    v = fmaf(v, t, a.z);
    v = fmaf(v, t, a.w);
    v = fmaf(v, t, b.x);
    v = fmaf(v, t, b.y);
    return v;
}

__global__ __launch_bounds__(256) void spline_eval_kernel(
    const float* __restrict__ x_new,
    const float4* __restrict__ wsA,
    const float2* __restrict__ wsB,
    float* __restrict__ out,
    int n4)
{
    __shared__ float4 cA[N_INT];       // 16368 B
    __shared__ float2 cB[N_INT];       //  8184 B  -> 24.5 KB total, 6 blk/CU

    // Coalesced table load: 1023 float4 + 1023 float2, 256 threads.
    for (int i = threadIdx.x; i < N_INT; i += 256) {
        cA[i] = wsA[i];
        cB[i] = wsB[i];
    }
    __syncthreads();

    const vfloat4* __restrict__ x4 = (const vfloat4*)x_new;
    vfloat4* __restrict__ o4 = (vfloat4*)out;

    int stride = gridDim.x * blockDim.x;
    for (int i = blockIdx.x * blockDim.x + threadIdx.x; i < n4; i += stride) {
        vfloat4 xv = __builtin_nontemporal_load(&x4[i]);
        vfloat4 r;
        r.x = eval_one(xv.x, cA, cB);
        r.y = eval_one(xv.y, cA, cB);
        r.z = eval_one(xv.z, cA, cB);
        r.w = eval_one(xv.w, cA, cB);
        __builtin_nontemporal_store(r, &o4[i]);
    }
}

extern "C" void kernel_launch(void* const* d_in, const int* in_sizes, int n_in,
                              void* d_out, int out_size, void* d_ws, size_t ws_size,
                              hipStream_t stream) {
    const float* x_new = (const float*)d_in[0];
    const float* knots = (const float*)d_in[1];
    const float* fv    = (const float*)d_in[2];
    float* out = (float*)d_out;

    float4* wsA = (float4*)d_ws;
    float2* wsB = (float2*)((char*)d_ws + WS_B_OFF);

    int n = in_sizes[0];          // 16,777,216
    int n4 = n >> 2;              // 4,194,304 float4 groups

    hipLaunchKernelGGL(build_table_kernel, dim3(1), dim3(1024), 0, stream,
                       knots, fv, wsA, wsB);

    // 4096 blocks x 256 threads -> 4 float4 iterations/thread; LDS 24.5 KB
    // -> 6 blocks/CU resident, plenty of waves to hide the LDS gather.
    hipLaunchKernelGGL(spline_eval_kernel, dim3(4096), dim3(256), 0, stream,
                       x_new, wsA, wsB, out, n4);
}

// Round 4
// 121.813 us; speedup vs baseline: 1.0336x; 1.0336x over previous
//
#include <hip/hip_runtime.h>

// QuinticHermiteSpline: 2^24 fp32 queries, 1024 uniform knots in [0,1].
// R4: fused single kernel (R1 structure + R3 refinements).
//   - Per-block LDS table build (runs concurrently across blocks; the R3
//     separate 1-block build kernel cost ~4-6 us of serialized launch+run).
//   - knots are linspace(0,1,1024) -> t = frac(x*1023): no x_l/inv_h/divide.
//   - Table: cA[i]={c5,c4,c3,c2} (float4), cB[i]={c1,c0} (float2), 24.5 KB.
//   - 512-thread blocks, grid 1024: 4 blocks/CU (98 KB LDS) x 8 waves
//     = 32 waves/CU, max occupancy. n4 = 1024*512*8 exactly -> no tail.
//   - Nontemporal float4 stream for x/out (128 MB HBM -> ~20 us floor).

#define N_KNOTS 1024
#define N_INT   1023

typedef float vfloat4 __attribute__((ext_vector_type(4)));

__device__ __forceinline__ float eval_one(float xq,
                                          const float4* __restrict__ cA,
                                          const float2* __restrict__ cB) {
    float s = xq * 1023.0f;
    int idx = (int)s;
    idx = min(max(idx, 0), N_INT - 1);
    float t = s - (float)idx;          // == frac(s) for in-range x
    float4 a = cA[idx];                // {c5, c4, c3, c2}
    float2 b = cB[idx];                // {c1, c0}
    float v = fmaf(a.x, t, a.y);
    v = fmaf(v, t, a.z);
    v = fmaf(v, t, a.w);
    v = fmaf(v, t, b.x);
    v = fmaf(v, t, b.y);
    return v;
}

__global__ __launch_bounds__(512) void quintic_spline_fused(
    const float* __restrict__ x_new,
    const float* __restrict__ knots,
    const float* __restrict__ fv,      // [3,1024]: y, dy, ddy
    float* __restrict__ out,
    int n4)
{
    __shared__ float4 cA[N_INT];       // 16368 B
    __shared__ float2 cB[N_INT];       //  8184 B -> 24552 B total

    const float* __restrict__ y   = fv;
    const float* __restrict__ dy  = fv + N_KNOTS;
    const float* __restrict__ ddy = fv + 2 * N_KNOTS;

    // Per-block table build: 1023 intervals, 512 threads -> 2 each.
    // Table inputs (16 KB) are L2-resident after the first few blocks.
    for (int i = threadIdx.x; i < N_INT; i += 512) {
        float xl   = knots[i];
        float h    = knots[i + 1] - xl;
        float yl   = y[i],   yr   = y[i + 1];
        float dyl  = dy[i],  dyr  = dy[i + 1];
        float ddyl = ddy[i], ddyr = ddy[i + 1];
        float dY = yr - yl;
        float h2 = 0.5f * h * h;
        float c5 =   6.0f * dY - 3.0f * h * (dyl + dyr)               + h2 * (ddyr - ddyl);
        float c4 = -15.0f * dY + h * (8.0f * dyl + 7.0f * dyr)        - h2 * (2.0f * ddyr - 3.0f * ddyl);
        float c3 =  10.0f * dY - 2.0f * h * (3.0f * dyl + 2.0f * dyr) + h2 * (ddyr - 3.0f * ddyl);
        cA[i] = make_float4(c5, c4, c3, h2 * ddyl);
        cB[i] = make_float2(h * dyl, yl);
    }
    __syncthreads();

    const vfloat4* __restrict__ x4 = (const vfloat4*)x_new;
    vfloat4* __restrict__ o4 = (vfloat4*)out;

    int stride = gridDim.x * blockDim.x;    // 524288
    for (int i = blockIdx.x * blockDim.x + threadIdx.x; i < n4; i += stride) {
        vfloat4 xv = __builtin_nontemporal_load(&x4[i]);
        vfloat4 r;
        r.x = eval_one(xv.x, cA, cB);
        r.y = eval_one(xv.y, cA, cB);
        r.z = eval_one(xv.z, cA, cB);
        r.w = eval_one(xv.w, cA, cB);
        __builtin_nontemporal_store(r, &o4[i]);
    }
}

extern "C" void kernel_launch(void* const* d_in, const int* in_sizes, int n_in,
                              void* d_out, int out_size, void* d_ws, size_t ws_size,
                              hipStream_t stream) {
    const float* x_new = (const float*)d_in[0];
    const float* knots = (const float*)d_in[1];
    const float* fv    = (const float*)d_in[2];
    float* out = (float*)d_out;

    int n = in_sizes[0];          // 16,777,216
    int n4 = n >> 2;              // 4,194,304 = 1024 * 512 * 8

    // 1024 blocks x 512 threads: 4 blocks/CU (98 KB LDS), 32 waves/CU.
    hipLaunchKernelGGL(quintic_spline_fused, dim3(1024), dim3(512), 0, stream,
                       x_new, knots, fv, out, n4);
}